// Round 3
// baseline (92.196 us; speedup 1.0000x reference)
//
#include <hip/hip_runtime.h>
#include <math.h>

// Problem constants (match reference setup_inputs)
constexpr int B = 4;
constexpr int S = 64;
constexpr int N = 65536;
constexpr float SLOPE = 7.0f;

// Tiling
constexpr int THREADS = 256;
constexpr int PTS_PER_THREAD = 4;                 // 4 consecutive points/thread
constexpr int PTS_PER_BLOCK = THREADS * PTS_PER_THREAD;   // 1024
constexpr int S_CHUNK = 16;                       // boxes per block

__global__ __launch_bounds__(THREADS) void box_weight_kernel(
    const float* __restrict__ pos,    // (B,S,3)
    const float* __restrict__ dims,   // (B,S,3)
    const float* __restrict__ rot,    // (B,S,1)
    const float* __restrict__ points, // (B,N,3)
    const int* __restrict__ vmask,    // (B,N) bool staged as int32
    float* __restrict__ out)          // (B,S,N)
{
    const int nchunk = blockIdx.x;    // 0 .. N/PTS_PER_BLOCK-1
    const int b      = blockIdx.y;    // 0 .. B-1
    const int schunk = blockIdx.z;    // 0 .. S/S_CHUNK-1
    const int t      = threadIdx.x;

    // Per-box params: c, s, tx, ty, tz, ax, ay, az  (a* = SLOPE*0.5*dim)
    __shared__ float bp[S_CHUNK][8];

    if (t < S_CHUNK) {
        const int s_idx = schunk * S_CHUNK + t;
        const int box   = b * S + s_idx;
        const float th  = rot[box];
        bp[t][0] = cosf(th);
        bp[t][1] = sinf(th);
        bp[t][2] = pos[box * 3 + 0];
        bp[t][3] = pos[box * 3 + 1];
        bp[t][4] = pos[box * 3 + 2];
        bp[t][5] = 0.5f * SLOPE * dims[box * 3 + 0];
        bp[t][6] = 0.5f * SLOPE * dims[box * 3 + 1];
        bp[t][7] = 0.5f * SLOPE * dims[box * 3 + 2];
    }
    __syncthreads();

    // ---- load 4 points (12 consecutive floats = 3 aligned float4) ----
    const int n0 = nchunk * PTS_PER_BLOCK + t * PTS_PER_THREAD;
    const float4* p4 =
        reinterpret_cast<const float4*>(points + (size_t)b * N * 3 + (size_t)n0 * 3);
    const float4 A = p4[0];
    const float4 Bv = p4[1];
    const float4 C = p4[2];

    float px[4] = {A.x, A.w, Bv.z, C.y};
    float py[4] = {A.y, Bv.x, Bv.w, C.z};
    float pz[4] = {A.z, Bv.y, C.x, C.w};

    // valid_mask: bool is staged as int32 by the harness ("integer -> const int*").
    // Zero out invalid points BEFORE the transform (matches ref's jnp.where).
    const int4 m = *reinterpret_cast<const int4*>(vmask + (size_t)b * N + n0);
    const int mk[4] = {m.x, m.y, m.z, m.w};
#pragma unroll
    for (int k = 0; k < 4; ++k) {
        if (!mk[k]) { px[k] = 0.f; py[k] = 0.f; pz[k] = 0.f; }
    }

    // ---- loop over the 16 boxes of this s-chunk ----
#pragma unroll 1
    for (int i = 0; i < S_CHUNK; ++i) {
        const float c  = bp[i][0];
        const float sn = bp[i][1];
        const float tx = bp[i][2];
        const float ty = bp[i][3];
        const float tz = bp[i][4];
        const float ax = bp[i][5];
        const float ay = bp[i][6];
        const float az = bp[i][7];

        float4 w;
        float* wp = &w.x;
#pragma unroll
        for (int k = 0; k < 4; ++k) {
            const float dx = px[k] - tx;
            const float dy = py[k] - ty;
            const float dz = pz[k] - tz;
            // R^T * d  (rotation about z):  inv(SE3) applied to homog point
            const float xo = fmaf(c, dx,  sn * dy);
            const float yo = fmaf(c, dy, -sn * dx);
            const float zo = dz;
            // logits: SLOPE*(dim/2 - |coord|) = a - SLOPE*|coord|
            const float lx = fmaf(-SLOPE, fabsf(xo), ax);
            const float ly = fmaf(-SLOPE, fabsf(yo), ay);
            const float lz = fmaf(-SLOPE, fabsf(zo), az);
            // sigmoid(lx)*sigmoid(ly)*sigmoid(lz) = 1/((1+e^-lx)(1+e^-ly)(1+e^-lz))
            // exp overflow saturates: denom=inf -> rcp=0 == sigmoid underflow. Safe.
            const float ex = __expf(-lx);
            const float ey = __expf(-ly);
            const float ez = __expf(-lz);
            const float denom = (1.f + ex) * (1.f + ey) * (1.f + ez);
            wp[k] = __frcp_rn(denom);
        }

        const int s_idx = schunk * S_CHUNK + i;
        float4* outp = reinterpret_cast<float4*>(
            out + ((size_t)b * S + s_idx) * (size_t)N + n0);
        *outp = w;
    }
}

extern "C" void kernel_launch(void* const* d_in, const int* in_sizes, int n_in,
                              void* d_out, int out_size, void* d_ws, size_t ws_size,
                              hipStream_t stream) {
    const float* pos    = (const float*)d_in[0];
    const float* dims   = (const float*)d_in[1];
    const float* rot    = (const float*)d_in[2];
    const float* points = (const float*)d_in[3];
    const int* vmask    = (const int*)d_in[4];
    float* out = (float*)d_out;

    dim3 grid(N / PTS_PER_BLOCK, B, S / S_CHUNK);  // (64, 4, 4)
    dim3 block(THREADS);
    box_weight_kernel<<<grid, block, 0, stream>>>(pos, dims, rot, points, vmask, out);
}